// Round 4
// baseline (388.217 us; speedup 1.0000x reference)
//
#include <hip/hip_runtime.h>
#include <hip/hip_bf16.h>

typedef __attribute__((ext_vector_type(8))) __bf16 bf16x8;
typedef __attribute__((ext_vector_type(4))) float floatx4;

constexpr int N_NODES = 100000;
constexpr int P_PERM  = 200000;

// ws layout (bytes)
constexpr size_t W2F_OFF  = 0;          // [16][2][4][64][8] bf16 = 131072 B
constexpr size_t WLF_OFF  = 131072;     // [2][4][64][8]  bf16 = 8192 B
constexpr size_t WD1F_OFF = 139264;     // [4][4][64][8]  bf16 = 16384 B
constexpr size_t BE_OFF   = 155648;     // [P*16] u8 packed = 3.2e6 B
constexpr size_t NFBF_OFF = 3355648;    // [100000][64] bf16 = 12.8e6 B
constexpr size_t WS_NEED_BE   = 3355648;
constexpr size_t WS_NEED_FULL = 3355648 + (size_t)N_NODES * 64 * 2;

// ---- fused prep ----
// blocks [0,6250): zero out
// blocks [6250,6554): weight fragment swizzle
// blocks [6554,9679): nfeat fp32 -> bf16
// blocks [9679,12804): be_pack = edge_feat_idx[e2p_col[.]] packed u8
__global__ void prep_all_kernel(float4* __restrict__ out,
                                const float* __restrict__ weights,
                                const float* __restrict__ w_lin,
                                const float* __restrict__ w_deg1,
                                const float* __restrict__ nfeat,
                                const int* __restrict__ e2p_col,
                                const int* __restrict__ edge_feat_idx,
                                __bf16* __restrict__ ws_bf) {
  int b = blockIdx.x;
  int t = threadIdx.x;
  if (b < 6250) {
    out[b * 256 + t] = make_float4(0.f, 0.f, 0.f, 0.f);
  } else if (b < 6554) {
    int i = (b - 6250) * 256 + t;
    if (i < 65536) {
      int j = i & 7, l = (i >> 3) & 63, ct = (i >> 9) & 3, ks = (i >> 11) & 1, a = i >> 12;
      int k = ks * 32 + (l >> 4) * 8 + j;
      int c = ct * 16 + (l & 15);
      ws_bf[W2F_OFF / 2 + i] = (__bf16)weights[k * 1024 + c * 16 + a];
    } else if (i < 65536 + 4096) {
      int i2 = i - 65536;
      int j = i2 & 7, l = (i2 >> 3) & 63, ct = (i2 >> 9) & 3, ks = (i2 >> 11) & 1;
      int k = ks * 32 + (l >> 4) * 8 + j;
      int c = ct * 16 + (l & 15);
      ws_bf[WLF_OFF / 2 + i2] = (__bf16)w_lin[c * 64 + k];
    } else if (i < 65536 + 4096 + 8192) {
      int i3 = i - 65536 - 4096;
      int j = i3 & 7, l = (i3 >> 3) & 63, ct = (i3 >> 9) & 3, ks = (i3 >> 11) & 3;
      int k = ks * 32 + (l >> 4) * 8 + j;
      int c = ct * 16 + (l & 15);
      ws_bf[WD1F_OFF / 2 + i3] = (__bf16)w_deg1[c * 128 + k];
    }
  } else if (b < 9679) {
    int i = (b - 6554) * 256 + t;
    if (i < N_NODES * 8) {
      float4 a = *(const float4*)(nfeat + (size_t)i * 8);
      float4 c = *(const float4*)(nfeat + (size_t)i * 8 + 4);
      bf16x8 o;
      o[0] = (__bf16)a.x; o[1] = (__bf16)a.y; o[2] = (__bf16)a.z; o[3] = (__bf16)a.w;
      o[4] = (__bf16)c.x; o[5] = (__bf16)c.y; o[6] = (__bf16)c.z; o[7] = (__bf16)c.w;
      *(bf16x8*)(ws_bf + NFBF_OFF / 2 + (size_t)i * 8) = o;
    }
  } else {
    int i = (b - 9679) * 256 + t;
    if (i < P_PERM * 4) {   // 800000 dwords, each covers 4 r's
      int4 ec = ((const int4*)e2p_col)[i];
      unsigned v = (unsigned)(edge_feat_idx[ec.x] & 0xff)
                 | ((unsigned)(edge_feat_idx[ec.y] & 0xff) << 8)
                 | ((unsigned)(edge_feat_idx[ec.z] & 0xff) << 16)
                 | ((unsigned)(edge_feat_idx[ec.w] & 0xff) << 24);
      ((unsigned*)((char*)ws_bf + BE_OFF))[i] = v;
    }
  }
}

struct IdxR { float2 nv[2]; float2 ev[2]; int2 nc[2]; };
struct GathR { bf16x8 nb[2][2][2]; };  // [pt][u][ks]

template <bool BF16FEAT>
__global__ __launch_bounds__(256, 3) void lrp_mfma_kernel(
    const float* __restrict__ nfeat,
    const float* __restrict__ degs,
    const float* __restrict__ n2p_val,
    const float* __restrict__ e2p_val,
    const float* __restrict__ pool_val,
    const float* __restrict__ bias,
    const float* __restrict__ w_deg0,
    const float* __restrict__ b_deg0,
    const float* __restrict__ b_deg1,
    const float* __restrict__ b_lin,
    const float* __restrict__ bond_emb,
    const int* __restrict__ n2p_col,
    const int* __restrict__ pool_row,
    const __bf16* __restrict__ ws_bf,
    float* __restrict__ out) {
  __shared__ __align__(16) __bf16 hs[4][2][16][72];
  __shared__ __align__(16) __bf16 sbond[4][72];

  const int t = threadIdx.x;
  const int w = t >> 6;
  const int l = t & 63;
  const int m = l & 15;
  const int q = l >> 4;
  const int pbw = blockIdx.x * 128 + w * 32;
  int pc[2];
  pc[0] = min(pbw + m, P_PERM - 1);
  pc[1] = min(pbw + 16 + m, P_PERM - 1);

  if (t < 256) sbond[t >> 6][t & 63] = (__bf16)bond_emb[t];
  __syncthreads();

  const __bf16* __restrict__ nfbf = ws_bf + NFBF_OFF / 2;
  const bf16x8* __restrict__ W2v  = (const bf16x8*)(ws_bf + W2F_OFF / 2);
  const bf16x8* __restrict__ WLv  = (const bf16x8*)(ws_bf + WLF_OFF / 2);
  const bf16x8* __restrict__ WD1v = (const bf16x8*)(ws_bf + WD1F_OFF / 2);
  const unsigned* __restrict__ bep = (const unsigned*)((const char*)ws_bf + BE_OFF);

  // startup: bond ids for all 16 a's, both p-tiles (linear addresses)
  unsigned be_dw[2][4];
  *(uint4*)&be_dw[0][0] = *(const uint4*)(bep + (size_t)pc[0] * 4);
  *(uint4*)&be_dw[1][0] = *(const uint4*)(bep + (size_t)pc[1] * 4);

  auto load_idx = [&](int r, IdxR& o) {
    int aa = r * 2;
    #pragma unroll
    for (int pt = 0; pt < 2; ++pt) {
      size_t rb = (size_t)pc[pt] * 16 + aa;
      o.nv[pt] = *(const float2*)(n2p_val + rb);
      o.ev[pt] = *(const float2*)(e2p_val + rb);
      o.nc[pt] = *(const int2*)(n2p_col + rb);
    }
  };
  auto load_gath = [&](const IdxR& id, GathR& g) {
    #pragma unroll
    for (int pt = 0; pt < 2; ++pt)
      #pragma unroll
      for (int u = 0; u < 2; ++u) {
        int nc = u ? id.nc[pt].y : id.nc[pt].x;
        #pragma unroll
        for (int ks = 0; ks < 2; ++ks) {
          int k0 = ks * 32 + q * 8;
          if (BF16FEAT) {
            g.nb[pt][u][ks] = *(const bf16x8*)(nfbf + (size_t)nc * 64 + k0);
          } else {
            float4 n0 = *(const float4*)(nfeat + (size_t)nc * 64 + k0);
            float4 n1 = *(const float4*)(nfeat + (size_t)nc * 64 + k0 + 4);
            bf16x8 o;
            o[0] = (__bf16)n0.x; o[1] = (__bf16)n0.y; o[2] = (__bf16)n0.z; o[3] = (__bf16)n0.w;
            o[4] = (__bf16)n1.x; o[5] = (__bf16)n1.y; o[6] = (__bf16)n1.z; o[7] = (__bf16)n1.w;
            g.nb[pt][u][ks] = o;
          }
        }
      }
  };

  floatx4 acc[2][4] = {};
  IdxR id_cur, id_nxt;
  GathR g_cur, g_nxt;
  load_idx(0, id_cur);
  load_idx(1, id_nxt);
  load_gath(id_cur, g_cur);

  #pragma unroll
  for (int r = 0; r < 8; ++r) {
    // prefetch round r+1 (clamped at the tail; redundant loads are harmless)
    load_gath(id_nxt, g_nxt);
    IdxR id_fut;
    load_idx(min(r + 2, 7), id_fut);

    const int aa = r * 2;
    #pragma unroll
    for (int u = 0; u < 2; ++u) {
      const int a = aa + u;
      // bond row ids for this a (from startup regs)
      int bea[2];
      #pragma unroll
      for (int pt = 0; pt < 2; ++pt)
        bea[pt] = (be_dw[pt][a >> 2] >> ((a & 3) * 8)) & 0xff;
      #pragma unroll
      for (int ks = 0; ks < 2; ++ks) {
        bf16x8 af[2];
        #pragma unroll
        for (int pt = 0; pt < 2; ++pt) {
          float nv = u ? id_cur.nv[pt].y : id_cur.nv[pt].x;
          float ev = u ? id_cur.ev[pt].y : id_cur.ev[pt].x;
          bf16x8 eb = *(const bf16x8*)&sbond[bea[pt]][ks * 32 + q * 8];
          #pragma unroll
          for (int j = 0; j < 8; ++j)
            af[pt][j] = (__bf16)fmaf(nv, (float)g_cur.nb[pt][u][ks][j],
                                     ev * (float)eb[j]);
        }
        #pragma unroll
        for (int ct = 0; ct < 4; ++ct) {
          bf16x8 bf = W2v[((a * 2 + ks) * 4 + ct) * 64 + l];
          acc[0][ct] = __builtin_amdgcn_mfma_f32_16x16x32_bf16(af[0], bf, acc[0][ct], 0, 0, 0);
          acc[1][ct] = __builtin_amdgcn_mfma_f32_16x16x32_bf16(af[1], bf, acc[1][ct], 0, 0, 0);
        }
      }
    }
    id_cur = id_nxt; id_nxt = id_fut; g_cur = g_nxt;
  }

  // ---- hr = relu(acc + bias) -> LDS (A-frag layout) -> @ w_lin^T ----
  floatx4 acc2[2][4] = {};
  {
    float biasv[4];
    #pragma unroll
    for (int ct = 0; ct < 4; ++ct) biasv[ct] = bias[ct * 16 + m];
    #pragma unroll
    for (int pt = 0; pt < 2; ++pt)
      #pragma unroll
      for (int ct = 0; ct < 4; ++ct)
        #pragma unroll
        for (int rr = 0; rr < 4; ++rr)
          hs[w][pt][q * 4 + rr][ct * 16 + m] =
              (__bf16)fmaxf(acc[pt][ct][rr] + biasv[ct], 0.0f);
    #pragma unroll
    for (int pt = 0; pt < 2; ++pt)
      #pragma unroll
      for (int ks = 0; ks < 2; ++ks) {
        bf16x8 af2 = *(const bf16x8*)&hs[w][pt][m][ks * 32 + q * 8];
        #pragma unroll
        for (int ct = 0; ct < 4; ++ct)
          acc2[pt][ct] = __builtin_amdgcn_mfma_f32_16x16x32_bf16(
              af2, WLv[(ks * 4 + ct) * 64 + l], acc2[pt][ct], 0, 0, 0);
      }
  }

  // ---- g-MLP ----
  floatx4 gacc[2][4] = {};
  {
    float ds[2][4];
    #pragma unroll
    for (int pt = 0; pt < 2; ++pt) {
      size_t rp = (size_t)pc[pt] * 16;
      #pragma unroll
      for (int jj = 0; jj < 4; ++jj)
        ds[pt][jj] = n2p_val[rp + 5 * jj] * degs[n2p_col[rp + 5 * jj]];
    }
    #pragma unroll
    for (int ks = 0; ks < 4; ++ks) {
      int k0 = ks * 32 + q * 8;
      float4 bb0 = *(const float4*)(b_deg0 + k0);
      float4 bb1 = *(const float4*)(b_deg0 + k0 + 4);
      float bk[8] = {bb0.x, bb0.y, bb0.z, bb0.w, bb1.x, bb1.y, bb1.z, bb1.w};
      bf16x8 af[2];
      #pragma unroll
      for (int j = 0; j < 8; ++j) {
        float4 wr = *(const float4*)(w_deg0 + (k0 + j) * 4);
        #pragma unroll
        for (int pt = 0; pt < 2; ++pt) {
          float v = bk[j];
          v = fmaf(ds[pt][0], wr.x, v);
          v = fmaf(ds[pt][1], wr.y, v);
          v = fmaf(ds[pt][2], wr.z, v);
          v = fmaf(ds[pt][3], wr.w, v);
          af[pt][j] = (__bf16)fmaxf(v, 0.0f);
        }
      }
      #pragma unroll
      for (int ct = 0; ct < 4; ++ct) {
        bf16x8 bf = WD1v[(ks * 4 + ct) * 64 + l];
        gacc[0][ct] = __builtin_amdgcn_mfma_f32_16x16x32_bf16(af[0], bf, gacc[0][ct], 0, 0, 0);
        gacc[1][ct] = __builtin_amdgcn_mfma_f32_16x16x32_bf16(af[1], bf, gacc[1][ct], 0, 0, 0);
      }
    }
  }

  // ---- h2 = (acc2 + b_lin) * (gacc + b_deg1); pooled scatter ----
  {
    float blv[4], bdv[4];
    #pragma unroll
    for (int ct = 0; ct < 4; ++ct) {
      blv[ct] = b_lin[ct * 16 + m];
      bdv[ct] = b_deg1[ct * 16 + m];
    }
    #pragma unroll
    for (int pt = 0; pt < 2; ++pt)
      #pragma unroll
      for (int rr = 0; rr < 4; ++rr) {
        int pp = pbw + pt * 16 + q * 4 + rr;
        if (pp < P_PERM) {
          int prow = pool_row[pp];
          float pv = pool_val[pp];
          float* orow = out + (size_t)prow * 64;
          #pragma unroll
          for (int ct = 0; ct < 4; ++ct) {
            float h2 = (acc2[pt][ct][rr] + blv[ct]) * (gacc[pt][ct][rr] + bdv[ct]);
            atomicAdd(orow + ct * 16 + m, pv * h2);
          }
        }
      }
  }
}

extern "C" void kernel_launch(void* const* d_in, const int* in_sizes, int n_in,
                              void* d_out, int out_size, void* d_ws, size_t ws_size,
                              hipStream_t stream) {
  const float* nfeat    = (const float*)d_in[0];
  const float* degs     = (const float*)d_in[1];
  const float* n2p_val  = (const float*)d_in[2];
  const float* e2p_val  = (const float*)d_in[3];
  const float* pool_val = (const float*)d_in[4];
  const float* weights  = (const float*)d_in[5];
  const float* bias     = (const float*)d_in[6];
  const float* w_deg0   = (const float*)d_in[7];
  const float* b_deg0   = (const float*)d_in[8];
  const float* w_deg1   = (const float*)d_in[9];
  const float* b_deg1   = (const float*)d_in[10];
  const float* w_lin    = (const float*)d_in[11];
  const float* b_lin    = (const float*)d_in[12];
  const float* bond_emb = (const float*)d_in[13];
  const int* edge_feat_idx = (const int*)d_in[14];
  const int* n2p_col    = (const int*)d_in[16];
  const int* e2p_col    = (const int*)d_in[18];
  const int* pool_row   = (const int*)d_in[19];

  float* out = (float*)d_out;
  __bf16* ws_bf = (__bf16*)d_ws;

  prep_all_kernel<<<12804, 256, 0, stream>>>((float4*)out, weights, w_lin,
                                             w_deg1, nfeat, e2p_col,
                                             edge_feat_idx, ws_bf);

  int grid = (P_PERM + 127) / 128;  // 1563
  if (ws_size >= WS_NEED_FULL) {
    lrp_mfma_kernel<true><<<grid, 256, 0, stream>>>(
        nfeat, degs, n2p_val, e2p_val, pool_val, bias, w_deg0, b_deg0,
        b_deg1, b_lin, bond_emb, n2p_col, pool_row, ws_bf, out);
  } else {
    lrp_mfma_kernel<false><<<grid, 256, 0, stream>>>(
        nfeat, degs, n2p_val, e2p_val, pool_val, bias, w_deg0, b_deg0,
        b_deg1, b_lin, bond_emb, n2p_col, pool_row, ws_bf, out);
  }
}

// Round 5
// 335.527 us; speedup vs baseline: 1.1570x; 1.1570x over previous
//
#include <hip/hip_runtime.h>
#include <hip/hip_bf16.h>

typedef __attribute__((ext_vector_type(8))) __bf16 bf16x8;
typedef __attribute__((ext_vector_type(4))) float floatx4;

constexpr int N_NODES = 100000;
constexpr int P_PERM  = 200000;

// ws layout (bytes)
constexpr size_t W2F_OFF  = 0;          // [16][2][4][64][8] bf16 = 131072 B (8192 B per a)
constexpr size_t WLF_OFF  = 131072;     // [2][4][64][8]  bf16 = 8192 B
constexpr size_t WD1F_OFF = 139264;     // [4][4][64][8]  bf16 = 16384 B
constexpr size_t BE_OFF   = 155648;     // [P*16] u8 packed = 3.2e6 B
constexpr size_t NFBF_OFF = 3355648;    // [100000][64] bf16 = 12.8e6 B
constexpr size_t WS_NEED_FULL = 3355648 + (size_t)N_NODES * 64 * 2;

// ---- fused prep ----
__global__ void prep_all_kernel(float4* __restrict__ out,
                                const float* __restrict__ weights,
                                const float* __restrict__ w_lin,
                                const float* __restrict__ w_deg1,
                                const float* __restrict__ nfeat,
                                const int* __restrict__ e2p_col,
                                const int* __restrict__ edge_feat_idx,
                                __bf16* __restrict__ ws_bf) {
  int b = blockIdx.x;
  int t = threadIdx.x;
  if (b < 6250) {
    out[b * 256 + t] = make_float4(0.f, 0.f, 0.f, 0.f);
  } else if (b < 6554) {
    int i = (b - 6250) * 256 + t;
    if (i < 65536) {
      int j = i & 7, l = (i >> 3) & 63, ct = (i >> 9) & 3, ks = (i >> 11) & 1, a = i >> 12;
      int k = ks * 32 + (l >> 4) * 8 + j;
      int c = ct * 16 + (l & 15);
      ws_bf[W2F_OFF / 2 + i] = (__bf16)weights[k * 1024 + c * 16 + a];
    } else if (i < 65536 + 4096) {
      int i2 = i - 65536;
      int j = i2 & 7, l = (i2 >> 3) & 63, ct = (i2 >> 9) & 3, ks = (i2 >> 11) & 1;
      int k = ks * 32 + (l >> 4) * 8 + j;
      int c = ct * 16 + (l & 15);
      ws_bf[WLF_OFF / 2 + i2] = (__bf16)w_lin[c * 64 + k];
    } else if (i < 65536 + 4096 + 8192) {
      int i3 = i - 65536 - 4096;
      int j = i3 & 7, l = (i3 >> 3) & 63, ct = (i3 >> 9) & 3, ks = (i3 >> 11) & 3;
      int k = ks * 32 + (l >> 4) * 8 + j;
      int c = ct * 16 + (l & 15);
      ws_bf[WD1F_OFF / 2 + i3] = (__bf16)w_deg1[c * 128 + k];
    }
  } else if (b < 9679) {
    int i = (b - 6554) * 256 + t;
    if (i < N_NODES * 8) {
      float4 a = *(const float4*)(nfeat + (size_t)i * 8);
      float4 c = *(const float4*)(nfeat + (size_t)i * 8 + 4);
      bf16x8 o;
      o[0] = (__bf16)a.x; o[1] = (__bf16)a.y; o[2] = (__bf16)a.z; o[3] = (__bf16)a.w;
      o[4] = (__bf16)c.x; o[5] = (__bf16)c.y; o[6] = (__bf16)c.z; o[7] = (__bf16)c.w;
      *(bf16x8*)(ws_bf + NFBF_OFF / 2 + (size_t)i * 8) = o;
    }
  } else {
    int i = (b - 9679) * 256 + t;
    if (i < P_PERM * 4) {
      int4 ec = ((const int4*)e2p_col)[i];
      unsigned v = (unsigned)(edge_feat_idx[ec.x] & 0xff)
                 | ((unsigned)(edge_feat_idx[ec.y] & 0xff) << 8)
                 | ((unsigned)(edge_feat_idx[ec.z] & 0xff) << 16)
                 | ((unsigned)(edge_feat_idx[ec.w] & 0xff) << 24);
      ((unsigned*)((char*)ws_bf + BE_OFF))[i] = v;
    }
  }
}

template <bool BF16FEAT>
__global__ __launch_bounds__(256, 6) void lrp_mfma_kernel(
    const float* __restrict__ nfeat,
    const float* __restrict__ degs,
    const float* __restrict__ n2p_val,
    const float* __restrict__ e2p_val,
    const float* __restrict__ pool_val,
    const float* __restrict__ bias,
    const float* __restrict__ w_deg0,
    const float* __restrict__ b_deg0,
    const float* __restrict__ b_deg1,
    const float* __restrict__ b_lin,
    const float* __restrict__ bond_emb,
    const int* __restrict__ n2p_col,
    const int* __restrict__ pool_row,
    const __bf16* __restrict__ ws_bf,
    float* __restrict__ out) {
  // W2 fragment double-buffer (8 KB per a-chunk), + hs transform tile + bond rows
  __shared__ __align__(16) char fraglds[2 * 8192];
  __shared__ __align__(16) __bf16 hs[4][16][72];
  __shared__ __align__(16) __bf16 sbond[4][72];

  const int t = threadIdx.x;
  const int w = t >> 6;
  const int l = t & 63;
  const int m = l & 15;
  const int q = l >> 4;
  const int pbw = blockIdx.x * 64 + w * 16;  // wave covers 16 p rows
  const int p = pbw + m;                     // this lane's A row (grid exact: p < P)

  const __bf16* __restrict__ nfbf = ws_bf + NFBF_OFF / 2;
  const bf16x8* __restrict__ WLv  = (const bf16x8*)(ws_bf + WLF_OFF / 2);
  const bf16x8* __restrict__ WD1v = (const bf16x8*)(ws_bf + WD1F_OFF / 2);
  const unsigned* __restrict__ bep = (const unsigned*)((const char*)ws_bf + BE_OFF);
  const char* __restrict__ W2bytes = (const char*)ws_bf + W2F_OFF;

  // bond ids for all 16 a's (one linear uint4 load)
  unsigned be_dw[4];
  *(uint4*)&be_dw[0] = *(const uint4*)(bep + (size_t)p * 4);

  if (t < 256) sbond[t >> 6][t & 63] = (__bf16)bond_emb[t];

  // W2 chunk staging: wave w stages bytes [w*2048, w*2048+2048) of the 8 KB chunk
  auto stage = [&](int a, int buf) {
    #pragma unroll
    for (int j = 0; j < 2; ++j) {
      const char* g = W2bytes + (size_t)a * 8192 + (w * 2 + j) * 1024 + l * 16;
      char* lds = &fraglds[buf * 8192 + (w * 2 + j) * 1024];
      __builtin_amdgcn_global_load_lds(
          (const __attribute__((address_space(1))) unsigned*)g,
          (__attribute__((address_space(3))) unsigned*)lds, 16, 0, 0);
    }
  };

  struct Idx { float nv, ev; int nc; };
  auto load_idx = [&](int a, Idx& o) {
    size_t r = (size_t)p * 16 + a;
    o.nv = n2p_val[r];
    o.ev = e2p_val[r];
    o.nc = n2p_col[r];
  };
  auto load_gath = [&](const Idx& id, bf16x8* g) {
    #pragma unroll
    for (int ks = 0; ks < 2; ++ks) {
      int k0 = ks * 32 + q * 8;
      if (BF16FEAT) {
        g[ks] = *(const bf16x8*)(nfbf + (size_t)id.nc * 64 + k0);
      } else {
        float4 n0 = *(const float4*)(nfeat + (size_t)id.nc * 64 + k0);
        float4 n1 = *(const float4*)(nfeat + (size_t)id.nc * 64 + k0 + 4);
        bf16x8 o;
        o[0] = (__bf16)n0.x; o[1] = (__bf16)n0.y; o[2] = (__bf16)n0.z; o[3] = (__bf16)n0.w;
        o[4] = (__bf16)n1.x; o[5] = (__bf16)n1.y; o[6] = (__bf16)n1.z; o[7] = (__bf16)n1.w;
        g[ks] = o;
      }
    }
  };

  floatx4 acc[4] = {{0,0,0,0},{0,0,0,0},{0,0,0,0},{0,0,0,0}};
  Idx id_cur, id_nxt, id_fut;
  bf16x8 g_cur[2], g_nxt[2];

  load_idx(0, id_cur);
  load_idx(1, id_nxt);
  load_gath(id_cur, g_cur);
  stage(0, 0);
  __syncthreads();   // sbond + chunk0 + (incidentally drains g_cur)

  #pragma unroll
  for (int a = 0; a < 16; ++a) {
    const int buf = a & 1;
    if (a < 15) {
      stage(a + 1, buf ^ 1);
      load_gath(id_nxt, g_nxt);
    }
    if (a < 14) load_idx(a + 2, id_fut);

    const int bea = (be_dw[a >> 2] >> ((a & 3) * 8)) & 0xff;
    const float nv = id_cur.nv;
    const float ev = id_cur.ev;
    #pragma unroll
    for (int ks = 0; ks < 2; ++ks) {
      bf16x8 eb = *(const bf16x8*)&sbond[bea][ks * 32 + q * 8];
      bf16x8 af;
      #pragma unroll
      for (int j = 0; j < 8; ++j)
        af[j] = (__bf16)fmaf(nv, (float)g_cur[ks][j], ev * (float)eb[j]);
      #pragma unroll
      for (int ct = 0; ct < 4; ++ct) {
        bf16x8 bfrag = *(const bf16x8*)&fraglds[buf * 8192 + ((ks * 4 + ct) * 64 + l) * 16];
        acc[ct] = __builtin_amdgcn_mfma_f32_16x16x32_bf16(af, bfrag, acc[ct], 0, 0, 0);
      }
    }
    if (a < 15) __syncthreads();  // drains next-round staging + gathers
    id_cur = id_nxt; id_nxt = id_fut;
    g_cur[0] = g_nxt[0]; g_cur[1] = g_nxt[1];
  }

  // ---- hr = relu(acc + bias) -> LDS (A-frag layout) -> @ w_lin^T ----
  floatx4 acc2[4] = {{0,0,0,0},{0,0,0,0},{0,0,0,0},{0,0,0,0}};
  {
    #pragma unroll
    for (int ct = 0; ct < 4; ++ct) {
      float bv = bias[ct * 16 + m];
      #pragma unroll
      for (int rr = 0; rr < 4; ++rr)
        hs[w][q * 4 + rr][ct * 16 + m] = (__bf16)fmaxf(acc[ct][rr] + bv, 0.0f);
    }
    #pragma unroll
    for (int ks = 0; ks < 2; ++ks) {
      bf16x8 af2 = *(const bf16x8*)&hs[w][m][ks * 32 + q * 8];
      #pragma unroll
      for (int ct = 0; ct < 4; ++ct)
        acc2[ct] = __builtin_amdgcn_mfma_f32_16x16x32_bf16(
            af2, WLv[(ks * 4 + ct) * 64 + l], acc2[ct], 0, 0, 0);
    }
  }

  // ---- g-MLP ----
  floatx4 gacc[4] = {{0,0,0,0},{0,0,0,0},{0,0,0,0},{0,0,0,0}};
  {
    float ds[4];
    size_t rp = (size_t)p * 16;
    #pragma unroll
    for (int jj = 0; jj < 4; ++jj)
      ds[jj] = n2p_val[rp + 5 * jj] * degs[n2p_col[rp + 5 * jj]];
    #pragma unroll
    for (int ks = 0; ks < 4; ++ks) {
      int k0 = ks * 32 + q * 8;
      float4 bb0 = *(const float4*)(b_deg0 + k0);
      float4 bb1 = *(const float4*)(b_deg0 + k0 + 4);
      float bk[8] = {bb0.x, bb0.y, bb0.z, bb0.w, bb1.x, bb1.y, bb1.z, bb1.w};
      bf16x8 af;
      #pragma unroll
      for (int j = 0; j < 8; ++j) {
        float4 wr = *(const float4*)(w_deg0 + (k0 + j) * 4);
        float v = bk[j];
        v = fmaf(ds[0], wr.x, v);
        v = fmaf(ds[1], wr.y, v);
        v = fmaf(ds[2], wr.z, v);
        v = fmaf(ds[3], wr.w, v);
        af[j] = (__bf16)fmaxf(v, 0.0f);
      }
      #pragma unroll
      for (int ct = 0; ct < 4; ++ct)
        gacc[ct] = __builtin_amdgcn_mfma_f32_16x16x32_bf16(
            af, WD1v[(ks * 4 + ct) * 64 + l], gacc[ct], 0, 0, 0);
    }
  }

  // ---- h2 = (acc2 + b_lin) * (gacc + b_deg1); pooled scatter ----
  {
    float blv[4], bdv[4];
    #pragma unroll
    for (int ct = 0; ct < 4; ++ct) {
      blv[ct] = b_lin[ct * 16 + m];
      bdv[ct] = b_deg1[ct * 16 + m];
    }
    #pragma unroll
    for (int rr = 0; rr < 4; ++rr) {
      int pp = pbw + q * 4 + rr;
      int prow = pool_row[pp];
      float pv = pool_val[pp];
      float* orow = out + (size_t)prow * 64;
      #pragma unroll
      for (int ct = 0; ct < 4; ++ct) {
        float h2 = (acc2[ct][rr] + blv[ct]) * (gacc[ct][rr] + bdv[ct]);
        atomicAdd(orow + ct * 16 + m, pv * h2);
      }
    }
  }
}

extern "C" void kernel_launch(void* const* d_in, const int* in_sizes, int n_in,
                              void* d_out, int out_size, void* d_ws, size_t ws_size,
                              hipStream_t stream) {
  const float* nfeat    = (const float*)d_in[0];
  const float* degs     = (const float*)d_in[1];
  const float* n2p_val  = (const float*)d_in[2];
  const float* e2p_val  = (const float*)d_in[3];
  const float* pool_val = (const float*)d_in[4];
  const float* weights  = (const float*)d_in[5];
  const float* bias     = (const float*)d_in[6];
  const float* w_deg0   = (const float*)d_in[7];
  const float* b_deg0   = (const float*)d_in[8];
  const float* w_deg1   = (const float*)d_in[9];
  const float* b_deg1   = (const float*)d_in[10];
  const float* w_lin    = (const float*)d_in[11];
  const float* b_lin    = (const float*)d_in[12];
  const float* bond_emb = (const float*)d_in[13];
  const int* edge_feat_idx = (const int*)d_in[14];
  const int* n2p_col    = (const int*)d_in[16];
  const int* e2p_col    = (const int*)d_in[18];
  const int* pool_row   = (const int*)d_in[19];

  float* out = (float*)d_out;
  __bf16* ws_bf = (__bf16*)d_ws;

  prep_all_kernel<<<12804, 256, 0, stream>>>((float4*)out, weights, w_lin,
                                             w_deg1, nfeat, e2p_col,
                                             edge_feat_idx, ws_bf);

  int grid = P_PERM / 64;  // 3125, exact
  if (ws_size >= WS_NEED_FULL) {
    lrp_mfma_kernel<true><<<grid, 256, 0, stream>>>(
        nfeat, degs, n2p_val, e2p_val, pool_val, bias, w_deg0, b_deg0,
        b_deg1, b_lin, bond_emb, n2p_col, pool_row, ws_bf, out);
  } else {
    lrp_mfma_kernel<false><<<grid, 256, 0, stream>>>(
        nfeat, degs, n2p_val, e2p_val, pool_val, bias, w_deg0, b_deg0,
        b_deg1, b_lin, bond_emb, n2p_col, pool_row, ws_bf, out);
  }
}

// Round 6
// 307.495 us; speedup vs baseline: 1.2625x; 1.0912x over previous
//
#include <hip/hip_runtime.h>
#include <hip/hip_bf16.h>

typedef __attribute__((ext_vector_type(8))) __bf16 bf16x8;
typedef __attribute__((ext_vector_type(4))) float floatx4;
typedef __attribute__((ext_vector_type(4))) int intx4;
typedef __attribute__((ext_vector_type(4))) unsigned uintx4;

constexpr int N_NODES = 100000;
constexpr int P_PERM  = 200000;

// ws layout (bytes)
constexpr size_t W2F_OFF  = 0;          // [16][2][4][64][8] bf16 = 131072 B (8192 B per a)
constexpr size_t WLF_OFF  = 131072;     // [2][4][64][8]  bf16 = 8192 B
constexpr size_t WD1F_OFF = 139264;     // [4][4][64][8]  bf16 = 16384 B
constexpr size_t BE_OFF   = 155648;     // [P*16] u8 packed = 3.2e6 B
constexpr size_t NFBF_OFF = 3355648;    // [100000][64] bf16 = 12.8e6 B
constexpr size_t WS_NEED_FULL = 3355648 + (size_t)N_NODES * 64 * 2;

// ---- fused prep (unchanged from R5) ----
__global__ void prep_all_kernel(float4* __restrict__ out,
                                const float* __restrict__ weights,
                                const float* __restrict__ w_lin,
                                const float* __restrict__ w_deg1,
                                const float* __restrict__ nfeat,
                                const int* __restrict__ e2p_col,
                                const int* __restrict__ edge_feat_idx,
                                __bf16* __restrict__ ws_bf) {
  int b = blockIdx.x;
  int t = threadIdx.x;
  if (b < 6250) {
    out[b * 256 + t] = make_float4(0.f, 0.f, 0.f, 0.f);
  } else if (b < 6554) {
    int i = (b - 6250) * 256 + t;
    if (i < 65536) {
      int j = i & 7, l = (i >> 3) & 63, ct = (i >> 9) & 3, ks = (i >> 11) & 1, a = i >> 12;
      int k = ks * 32 + (l >> 4) * 8 + j;
      int c = ct * 16 + (l & 15);
      ws_bf[W2F_OFF / 2 + i] = (__bf16)weights[k * 1024 + c * 16 + a];
    } else if (i < 65536 + 4096) {
      int i2 = i - 65536;
      int j = i2 & 7, l = (i2 >> 3) & 63, ct = (i2 >> 9) & 3, ks = (i2 >> 11) & 1;
      int k = ks * 32 + (l >> 4) * 8 + j;
      int c = ct * 16 + (l & 15);
      ws_bf[WLF_OFF / 2 + i2] = (__bf16)w_lin[c * 64 + k];
    } else if (i < 65536 + 4096 + 8192) {
      int i3 = i - 65536 - 4096;
      int j = i3 & 7, l = (i3 >> 3) & 63, ct = (i3 >> 9) & 3, ks = (i3 >> 11) & 3;
      int k = ks * 32 + (l >> 4) * 8 + j;
      int c = ct * 16 + (l & 15);
      ws_bf[WD1F_OFF / 2 + i3] = (__bf16)w_deg1[c * 128 + k];
    }
  } else if (b < 9679) {
    int i = (b - 6554) * 256 + t;
    if (i < N_NODES * 8) {
      float4 a = *(const float4*)(nfeat + (size_t)i * 8);
      float4 c = *(const float4*)(nfeat + (size_t)i * 8 + 4);
      bf16x8 o;
      o[0] = (__bf16)a.x; o[1] = (__bf16)a.y; o[2] = (__bf16)a.z; o[3] = (__bf16)a.w;
      o[4] = (__bf16)c.x; o[5] = (__bf16)c.y; o[6] = (__bf16)c.z; o[7] = (__bf16)c.w;
      *(bf16x8*)(ws_bf + NFBF_OFF / 2 + (size_t)i * 8) = o;
    }
  } else {
    int i = (b - 9679) * 256 + t;
    if (i < P_PERM * 4) {
      int4 ec = ((const int4*)e2p_col)[i];
      unsigned v = (unsigned)(edge_feat_idx[ec.x] & 0xff)
                 | ((unsigned)(edge_feat_idx[ec.y] & 0xff) << 8)
                 | ((unsigned)(edge_feat_idx[ec.z] & 0xff) << 16)
                 | ((unsigned)(edge_feat_idx[ec.w] & 0xff) << 24);
      ((unsigned*)((char*)ws_bf + BE_OFF))[i] = v;
    }
  }
}

template <bool BF16FEAT>
__global__ __launch_bounds__(256, 4) void lrp_mfma_kernel(
    const float* __restrict__ nfeat,
    const float* __restrict__ degs,
    const float* __restrict__ n2p_val,
    const float* __restrict__ e2p_val,
    const float* __restrict__ pool_val,
    const float* __restrict__ bias,
    const float* __restrict__ w_deg0,
    const float* __restrict__ b_deg0,
    const float* __restrict__ b_deg1,
    const float* __restrict__ b_lin,
    const float* __restrict__ bond_emb,
    const int* __restrict__ n2p_col,
    const int* __restrict__ pool_row,
    const __bf16* __restrict__ ws_bf,
    float* __restrict__ out) {
  __shared__ __align__(16) char fraglds[2][8192];
  __shared__ __align__(16) __bf16 sbond[4][72];
  __shared__ __align__(16) float swdeg0[128][4];
  __shared__ float sbd0[128];
  __shared__ float sbias[64];
  __shared__ float sblin[64];
  __shared__ float sbd1[64];
  __shared__ __align__(16) __bf16 hs[4][2][16][72];

  const int t = threadIdx.x;
  const int w = t >> 6;
  const int l = t & 63;
  const int m = l & 15;
  const int q = l >> 4;
  const int pb0 = blockIdx.x * 256 + w * 32;  // block covers 256? no: 128 p's -> see grid
  // NOTE: grid is ceil(P/128); block covers 128 p's: wave w gets [bid*128 + w*32, +32)
  const int pbase = blockIdx.x * 128 + w * 32;
  int pb[2]  = {pbase, pbase + 16};
  bool valid[2];
  int pbc[2];
  #pragma unroll
  for (int pt = 0; pt < 2; ++pt) {
    valid[pt] = pb[pt] < P_PERM;
    pbc[pt] = valid[pt] ? pb[pt] : (P_PERM - 16);
  }

  // ---- stage small LDS tables ----
  if (t < 256) sbond[t >> 6][t & 63] = (__bf16)bond_emb[t];
  if (t < 128) {
    *(float4*)&swdeg0[t][0] = *(const float4*)(w_deg0 + t * 4);
    sbd0[t] = b_deg0[t];
  } else if (t < 192) {
    int c = t - 128;
    sbias[c] = bias[c]; sblin[c] = b_lin[c]; sbd1[c] = b_deg1[c];
  }

  const __bf16* __restrict__ nfbf = ws_bf + NFBF_OFF / 2;
  const bf16x8* __restrict__ WLv  = (const bf16x8*)(ws_bf + WLF_OFF / 2);
  const bf16x8* __restrict__ WD1v = (const bf16x8*)(ws_bf + WD1F_OFF / 2);
  const unsigned* __restrict__ bep = (const unsigned*)((const char*)ws_bf + BE_OFF);
  const char* __restrict__ W2bytes = (const char*)ws_bf + W2F_OFF;

  // ---- wave-cooperative idx preloads: 1 KB per (array, pt) covers all 16 rounds ----
  intx4 nvx[2], evx[2], ncx[2];
  int bex[2];
  #pragma unroll
  for (int pt = 0; pt < 2; ++pt) {
    size_t rb = (size_t)pbc[pt] * 16;
    nvx[pt] = *(const intx4*)(n2p_val + rb + 4 * l);
    evx[pt] = *(const intx4*)(e2p_val + rb + 4 * l);
    ncx[pt] = *(const intx4*)(n2p_col + rb + 4 * l);
    bex[pt] = (int)bep[(size_t)pbc[pt] * 4 + l];
  }
  const int selbase = m * 16;  // byte selector base: src_lane = m*4 + (a>>2)

  // W2 chunk staging: wave w stages its quarter of the 8 KB chunk
  auto stage = [&](int a, int buf) {
    #pragma unroll
    for (int j = 0; j < 2; ++j) {
      const char* g = W2bytes + (size_t)a * 8192 + (w * 2 + j) * 1024 + l * 16;
      char* lds = &fraglds[buf][(w * 2 + j) * 1024];
      __builtin_amdgcn_global_load_lds(
          (const __attribute__((address_space(1))) unsigned*)g,
          (__attribute__((address_space(3))) unsigned*)lds, 16, 0, 0);
    }
  };
  auto gath = [&](int nc, bf16x8* g) {
    #pragma unroll
    for (int ks = 0; ks < 2; ++ks) {
      int k0 = ks * 32 + q * 8;
      if (BF16FEAT) {
        g[ks] = *(const bf16x8*)(nfbf + (size_t)nc * 64 + k0);
      } else {
        float4 n0 = *(const float4*)(nfeat + (size_t)nc * 64 + k0);
        float4 n1 = *(const float4*)(nfeat + (size_t)nc * 64 + k0 + 4);
        bf16x8 o;
        o[0] = (__bf16)n0.x; o[1] = (__bf16)n0.y; o[2] = (__bf16)n0.z; o[3] = (__bf16)n0.w;
        o[4] = (__bf16)n1.x; o[5] = (__bf16)n1.y; o[6] = (__bf16)n1.z; o[7] = (__bf16)n1.w;
        g[ks] = o;
      }
    }
  };

  floatx4 acc[2][4] = {};
  float dsreg[2][4];
  float nv0[2], ev0[2];
  int nc0[2], be0[2];
  bf16x8 g_cur[2][2], g_nxt[2][2];

  // prologue: round-0 idx via bpermute, gathers, stage chunk 0
  #pragma unroll
  for (int pt = 0; pt < 2; ++pt) {
    nv0[pt] = __int_as_float(__builtin_amdgcn_ds_bpermute(selbase, nvx[pt][0]));
    ev0[pt] = __int_as_float(__builtin_amdgcn_ds_bpermute(selbase, evx[pt][0]));
    nc0[pt] = __builtin_amdgcn_ds_bpermute(selbase, ncx[pt][0]);
    be0[pt] = (__builtin_amdgcn_ds_bpermute(selbase, bex[pt])) & 0xff;
    gath(nc0[pt], g_cur[pt]);
  }
  stage(0, 0);
  __syncthreads();

  #pragma unroll
  for (int a = 0; a < 16; ++a) {
    const int buf = a & 1;
    float nv1[2], ev1[2];
    int nc1[2], be1[2];
    if (a < 15) {
      const int an = a + 1;
      const int sel1 = selbase + (an >> 2) * 4;
      const int sl = an & 3;
      #pragma unroll
      for (int pt = 0; pt < 2; ++pt) {
        nv1[pt] = __int_as_float(__builtin_amdgcn_ds_bpermute(sel1, nvx[pt][sl]));
        ev1[pt] = __int_as_float(__builtin_amdgcn_ds_bpermute(sel1, evx[pt][sl]));
        nc1[pt] = __builtin_amdgcn_ds_bpermute(sel1, ncx[pt][sl]);
        be1[pt] = (__builtin_amdgcn_ds_bpermute(sel1, bex[pt]) >> (sl * 8)) & 0xff;
      }
      stage(a + 1, buf ^ 1);
      #pragma unroll
      for (int pt = 0; pt < 2; ++pt) gath(nc1[pt], g_nxt[pt]);
    }

    // compute round a
    bf16x8 afv[2][2];
    #pragma unroll
    for (int pt = 0; pt < 2; ++pt) {
      #pragma unroll
      for (int ks = 0; ks < 2; ++ks) {
        bf16x8 eb = *(const bf16x8*)&sbond[be0[pt]][ks * 32 + q * 8];
        bf16x8 af;
        #pragma unroll
        for (int j = 0; j < 8; ++j)
          af[j] = (__bf16)fmaf(nv0[pt], (float)g_cur[pt][ks][j],
                               ev0[pt] * (float)eb[j]);
        afv[pt][ks] = af;
      }
    }
    #pragma unroll
    for (int ks = 0; ks < 2; ++ks)
      #pragma unroll
      for (int ct = 0; ct < 4; ++ct) {
        bf16x8 frag = *(const bf16x8*)&fraglds[buf][((ks * 4 + ct) * 64 + l) * 16];
        acc[0][ct] = __builtin_amdgcn_mfma_f32_16x16x32_bf16(afv[0][ks], frag, acc[0][ct], 0, 0, 0);
        acc[1][ct] = __builtin_amdgcn_mfma_f32_16x16x32_bf16(afv[1][ks], frag, acc[1][ct], 0, 0, 0);
      }

    // deg_sel fold at a = 0,5,10,15 (reuses bpermuted nv/nc)
    if (a == 0 || a == 5 || a == 10 || a == 15) {
      const int jj = a / 5;
      #pragma unroll
      for (int pt = 0; pt < 2; ++pt)
        dsreg[pt][jj] = nv0[pt] * degs[nc0[pt]];
    }

    if (a < 15) {
      __syncthreads();
      #pragma unroll
      for (int pt = 0; pt < 2; ++pt) {
        nv0[pt] = nv1[pt]; ev0[pt] = ev1[pt]; nc0[pt] = nc1[pt]; be0[pt] = be1[pt];
        g_cur[pt][0] = g_nxt[pt][0]; g_cur[pt][1] = g_nxt[pt][1];
      }
    }
  }

  // ---- hr = relu(acc + bias) -> LDS (A-frag layout) -> @ w_lin^T ----
  floatx4 acc2[2][4] = {};
  {
    #pragma unroll
    for (int pt = 0; pt < 2; ++pt)
      #pragma unroll
      for (int ct = 0; ct < 4; ++ct) {
        float bv = sbias[ct * 16 + m];
        #pragma unroll
        for (int rr = 0; rr < 4; ++rr)
          hs[w][pt][q * 4 + rr][ct * 16 + m] =
              (__bf16)fmaxf(acc[pt][ct][rr] + bv, 0.0f);
      }
    #pragma unroll
    for (int pt = 0; pt < 2; ++pt)
      #pragma unroll
      for (int ks = 0; ks < 2; ++ks) {
        bf16x8 af2 = *(const bf16x8*)&hs[w][pt][m][ks * 32 + q * 8];
        #pragma unroll
        for (int ct = 0; ct < 4; ++ct) {
          bf16x8 frag = WLv[(ks * 4 + ct) * 64 + l];
          acc2[pt][ct] = __builtin_amdgcn_mfma_f32_16x16x32_bf16(af2, frag, acc2[pt][ct], 0, 0, 0);
        }
      }
  }

  // ---- g-MLP (w_deg0/b_deg0 from LDS) ----
  floatx4 gacc[2][4] = {};
  #pragma unroll
  for (int ks = 0; ks < 4; ++ks) {
    const int k0 = ks * 32 + q * 8;
    bf16x8 af[2];
    #pragma unroll
    for (int j = 0; j < 8; ++j) {
      int k = k0 + j;
      float4 wr = *(const float4*)&swdeg0[k][0];
      float bk = sbd0[k];
      #pragma unroll
      for (int pt = 0; pt < 2; ++pt) {
        float v = bk;
        v = fmaf(dsreg[pt][0], wr.x, v);
        v = fmaf(dsreg[pt][1], wr.y, v);
        v = fmaf(dsreg[pt][2], wr.z, v);
        v = fmaf(dsreg[pt][3], wr.w, v);
        af[pt][j] = (__bf16)fmaxf(v, 0.0f);
      }
    }
    #pragma unroll
    for (int ct = 0; ct < 4; ++ct) {
      bf16x8 frag = WD1v[(ks * 4 + ct) * 64 + l];
      gacc[0][ct] = __builtin_amdgcn_mfma_f32_16x16x32_bf16(af[0], frag, gacc[0][ct], 0, 0, 0);
      gacc[1][ct] = __builtin_amdgcn_mfma_f32_16x16x32_bf16(af[1], frag, gacc[1][ct], 0, 0, 0);
    }
  }

  // ---- h2 = (acc2 + b_lin) * (gacc + b_deg1); pooled scatter ----
  #pragma unroll
  for (int pt = 0; pt < 2; ++pt) {
    if (!valid[pt]) continue;
    intx4   pr4 = *(const intx4*)(pool_row + pb[pt] + q * 4);
    floatx4 pv4 = *(const floatx4*)(pool_val + pb[pt] + q * 4);
    #pragma unroll
    for (int rr = 0; rr < 4; ++rr) {
      float* orow = out + (size_t)pr4[rr] * 64;
      float pv = pv4[rr];
      #pragma unroll
      for (int ct = 0; ct < 4; ++ct) {
        float h2 = (acc2[pt][ct][rr] + sblin[ct * 16 + m]) *
                   (gacc[pt][ct][rr] + sbd1[ct * 16 + m]);
        atomicAdd(orow + ct * 16 + m, pv * h2);
      }
    }
  }
}

extern "C" void kernel_launch(void* const* d_in, const int* in_sizes, int n_in,
                              void* d_out, int out_size, void* d_ws, size_t ws_size,
                              hipStream_t stream) {
  const float* nfeat    = (const float*)d_in[0];
  const float* degs     = (const float*)d_in[1];
  const float* n2p_val  = (const float*)d_in[2];
  const float* e2p_val  = (const float*)d_in[3];
  const float* pool_val = (const float*)d_in[4];
  const float* weights  = (const float*)d_in[5];
  const float* bias     = (const float*)d_in[6];
  const float* w_deg0   = (const float*)d_in[7];
  const float* b_deg0   = (const float*)d_in[8];
  const float* w_deg1   = (const float*)d_in[9];
  const float* b_deg1   = (const float*)d_in[10];
  const float* w_lin    = (const float*)d_in[11];
  const float* b_lin    = (const float*)d_in[12];
  const float* bond_emb = (const float*)d_in[13];
  const int* edge_feat_idx = (const int*)d_in[14];
  const int* n2p_col    = (const int*)d_in[16];
  const int* e2p_col    = (const int*)d_in[18];
  const int* pool_row   = (const int*)d_in[19];

  float* out = (float*)d_out;
  __bf16* ws_bf = (__bf16*)d_ws;

  prep_all_kernel<<<12804, 256, 0, stream>>>((float4*)out, weights, w_lin,
                                             w_deg1, nfeat, e2p_col,
                                             edge_feat_idx, ws_bf);

  int grid = (P_PERM + 127) / 128;  // 1563
  if (ws_size >= WS_NEED_FULL) {
    lrp_mfma_kernel<true><<<grid, 256, 0, stream>>>(
        nfeat, degs, n2p_val, e2p_val, pool_val, bias, w_deg0, b_deg0,
        b_deg1, b_lin, bond_emb, n2p_col, pool_row, ws_bf, out);
  } else {
    lrp_mfma_kernel<false><<<grid, 256, 0, stream>>>(
        nfeat, degs, n2p_val, e2p_val, pool_val, bias, w_deg0, b_deg0,
        b_deg1, b_lin, bond_emb, n2p_col, pool_row, ws_bf, out);
  }
}